// Round 1
// baseline (462.182 us; speedup 1.0000x reference)
//
#include <hip/hip_runtime.h>
#include <math.h>

typedef __bf16 bf16_t;
typedef __bf16 bf16x8 __attribute__((ext_vector_type(8)));
typedef float  f32x16 __attribute__((ext_vector_type(16)));

#define FRAME 2048
#define NOUT  1580

// LDS layout (bytes):
// [0,     33792) : arrA[8][2112] bf16 phase copies   | overlay: partial[4][2112] f32
// [33792, 39936) : arrB[3072] bf16 (XOR-swizzled)    | overlay: dbuf[2048] f32 @ [33792,41984)
// [41984, 50180) : s_arr[2049] f32
// [50192, 50320) : wtot[32] f32
// total 50368 B -> 3 blocks/CU

__global__ __launch_bounds__(256, 3) void yingram_kernel(
    const float* __restrict__ x, float* __restrict__ out)
{
    __shared__ alignas(16) char smem[50368];
    bf16_t* arrA    = (bf16_t*)smem;               // [8][2112]
    bf16_t* arrB    = (bf16_t*)(smem + 33792);     // [3072] physical (swizzled)
    float*  partial = (float*)smem;                // [4][2112]
    float*  dbuf    = (float*)(smem + 33792);      // [2048]
    float*  s_arr   = (float*)(smem + 41984);      // [2049]
    float*  wtot    = (float*)(smem + 50192);      // [8][4]

    const int tid  = threadIdx.x;
    const int lane = tid & 63;
    const int w    = tid >> 6;
    const int q    = lane >> 5;
    const int col  = lane & 31;
    const int frame = blockIdx.x;
    const float* xp = x + (size_t)frame * FRAME;

    // ---- zero stage region [0, 40064) : 2504 uint4 ----
    for (int i = tid; i < 2504; i += 256)
        ((uint4*)smem)[i] = make_uint4(0u, 0u, 0u, 0u);

    // ---- load frame (strided ownership n = tid + 256e, coalesced) ----
    float xv[8];
    #pragma unroll
    for (int e = 0; e < 8; ++e) xv[e] = xp[tid + 256 * e];

    __syncthreads();

    // ---- scatter bf16 phase copies (A: 8 phases) + swizzled B copy ----
    #pragma unroll
    for (int e = 0; e < 8; ++e) {
        bf16_t v = (bf16_t)xv[e];
        int n = tid + 256 * e;
        #pragma unroll
        for (int p = 0; p < 8; ++p)
            arrA[p * 2112 + n + 32 - p] = v;   // arrA[p][m] = xt[m-32+p]
        int m  = n + 1;                         // arrB logical m holds xt[m-1]
        int B  = m >> 3;
        int Bs = B ^ ((B >> 2) & 7);
        arrB[8 * Bs + (m & 7)] = v;
    }

    // ---- prefix sum of squares -> s_arr[0..2048] (8 stripe shuffle-scans) ----
    {
        float iw[8];
        #pragma unroll
        for (int e = 0; e < 8; ++e) {
            float v = xv[e] * xv[e];
            #pragma unroll
            for (int off = 1; off < 64; off <<= 1) {
                float o = __shfl_up(v, (unsigned)off, 64);
                if (lane >= off) v += o;
            }
            iw[e] = v;
            if (lane == 63) wtot[e * 4 + w] = v;
        }
        __syncthreads();
        float run = 0.f;
        #pragma unroll
        for (int e = 0; e < 8; ++e) {
            float t0 = wtot[e*4+0], t1 = wtot[e*4+1], t2 = wtot[e*4+2], t3 = wtot[e*4+3];
            float pre = (w > 0 ? t0 : 0.f) + (w > 1 ? t1 : 0.f) + (w > 2 ? t2 : 0.f);
            s_arr[tid + 256 * e + 1] = run + pre + iw[e];
            run += t0 + t1 + t2 + t3;
        }
        if (tid == 0) s_arr[0] = 0.f;
    }
    __syncthreads();

    // ---- MFMA correlation ----
    // D[i][j] = r[k0 + 32*j - i]; tiles k0 = 31 (lags 0..1023), 1055 (1024..2047)
    // A[i][c] = xt[n0+c+i] from phase copy p = i&7 (16B-aligned b128)
    // B[c][j] = xt[n0+c+k0+32j] from swizzled arrB
    const int p = col & 7;
    const bf16_t* aBase = arrA + p * 2112 + 8 * q + (col & ~7);
    f32x16 acc0, acc1;
    #pragma unroll
    for (int v = 0; v < 16; ++v) { acc0[v] = 0.f; acc1[v] = 0.f; }

    for (int k = w; k < 130; k += 4) {
        bf16x8 af = *(const bf16x8*)(aBase + 16 * k);
        int m0 = 16 * k + 8 * q + 32 * col;       // logical arrB index, tile0
        int B0 = m0 >> 3;
        int s0 = B0 ^ ((B0 >> 2) & 7);
        bf16x8 bf0 = *(const bf16x8*)(arrB + 8 * s0);
        acc0 = __builtin_amdgcn_mfma_f32_32x32x16_bf16(af, bf0, acc0, 0, 0, 0);
        if (k < 65) {
            int m1 = m0 + 1024;
            int B1 = m1 >> 3;
            int s1 = B1 ^ ((B1 >> 2) & 7);
            bf16x8 bf1 = *(const bf16x8*)(arrB + 8 * s1);
            acc1 = __builtin_amdgcn_mfma_f32_32x32x16_bf16(af, bf1, acc1, 0, 0, 0);
        }
    }

    __syncthreads();   // all waves done reading stage region

    // ---- write per-wave partials (overlay), pad-swizzled to avoid 32-stride conflicts ----
    #pragma unroll
    for (int v = 0; v < 16; ++v) {
        int row  = (v & 3) + 8 * (v >> 2) + 4 * q;   // C/D: col=lane&31, row per m74/m101
        int lag0 = 31   + 32 * col - row;            // [0,1024)
        int lag1 = 1055 + 32 * col - row;            // [1024,2048)
        partial[w * 2112 + lag0 + (lag0 >> 5)] = acc0[v];
        partial[w * 2112 + lag1 + (lag1 >> 5)] = acc1[v];
    }
    __syncthreads();

    // ---- reduce partials, d_raw, cumulative-mean normalize -> dbuf ----
    float dr[8];
    const float sW = s_arr[2048];
    #pragma unroll
    for (int e = 0; e < 8; ++e) {
        int t = tid + 256 * e;
        int idx = t + (t >> 5);
        float r = partial[idx] + partial[2112 + idx] +
                  partial[2 * 2112 + idx] + partial[3 * 2112 + idx];
        float d = s_arr[2048 - t] + sW - s_arr[t] - 2.f * r;
        dr[e] = (t == 0) ? 0.f : d;
    }
    {
        float iw[8];
        #pragma unroll
        for (int e = 0; e < 8; ++e) {
            float v = dr[e];
            #pragma unroll
            for (int off = 1; off < 64; off <<= 1) {
                float o = __shfl_up(v, (unsigned)off, 64);
                if (lane >= off) v += o;
            }
            iw[e] = v;
            if (lane == 63) wtot[e * 4 + w] = v;
        }
        __syncthreads();
        float run = 0.f;
        #pragma unroll
        for (int e = 0; e < 8; ++e) {
            float t0 = wtot[e*4+0], t1 = wtot[e*4+1], t2 = wtot[e*4+2], t3 = wtot[e*4+3];
            float pre = (w > 0 ? t0 : 0.f) + (w > 1 ? t1 : 0.f) + (w > 2 ? t2 : 0.f);
            float cum = run + pre + iw[e];           // inclusive cumsum at t
            int t = tid + 256 * e;
            dbuf[t] = (float)t * dr[e] / (cum + 1e-7f);
            run += t0 + t1 + t2 + t3;
        }
    }
    __syncthreads();

    // ---- gather-interpolate onto midi grid (constants in fp64, mirrors numpy) ----
    float* op = out + (size_t)frame * NOUT;
    for (int m = tid; m < NOUT; m += 256) {
        double midi = 5.0 + (double)m * 0.05;               // np.arange fill
        float  mf   = (float)midi;                          // .astype(float32)
        double lag64 = 22050.0 / (440.0 * exp2(((double)mf - 69.0) / 12.0));
        float  lag  = (float)lag64;                         // .astype(float32)
        float  cf = ceilf(lag), ff = floorf(lag);
        float  dc = dbuf[(int)cf], df = dbuf[(int)ff];
        float  y  = (lag - ff) * (dc - df) / (cf - ff) + df;
        op[m] = y;
    }
}

extern "C" void kernel_launch(void* const* d_in, const int* in_sizes, int n_in,
                              void* d_out, int out_size, void* d_ws, size_t ws_size,
                              hipStream_t stream) {
    const float* x = (const float*)d_in[0];
    float* out = (float*)d_out;
    int frames = in_sizes[0] / FRAME;   // 16384
    yingram_kernel<<<dim3(frames), dim3(256), 0, stream>>>(x, out);
}

// Round 2
// 325.136 us; speedup vs baseline: 1.4215x; 1.4215x over previous
//
#include <hip/hip_runtime.h>
#include <math.h>

typedef __bf16 bf16_t;
typedef __bf16 bf16x8 __attribute__((ext_vector_type(8)));
typedef float  f32x4  __attribute__((ext_vector_type(4)));
typedef float  f32x16 __attribute__((ext_vector_type(16)));
typedef unsigned int u32;
typedef u32 u32x4 __attribute__((ext_vector_type(4)));

#define FRAME 2048
#define NOUT  1580

#define A_STRIDE 2120            // bf16 elements per phase copy (offset 4240B = 16 mod 128: bank-uniform)
#define P_STRIDE 2304            // partial row floats: 2048 + 4*(2048/32), keeps float4 alignment
#define B_OFF_BYTES 36864        // = 4*P_STRIDE*4 (partial overlay region end)
#define DBUF_OFF_BYTES 36864     // dbuf overlays arrB
#define SARR_OFF_BYTES 45056
#define WTOT_OFF_BYTES 53264
#define SMEM_BYTES 53280         // ~53.3KB -> 3 blocks/CU

__global__ __launch_bounds__(256, 3) void yingram_kernel(
    const float* __restrict__ x, float* __restrict__ out,
    const int4* __restrict__ tbl, int use_tbl)
{
    __shared__ alignas(16) char smem[SMEM_BYTES];
    bf16_t* arrA    = (bf16_t*)smem;                      // [8][A_STRIDE]
    char*   arrBb   = smem + B_OFF_BYTES;                 // phys slots: 8*(B + (B>>3)) bf16
    float*  partial = (float*)smem;                       // [4][P_STRIDE] overlay
    float*  dbuf    = (float*)(smem + DBUF_OFF_BYTES);    // [2048] overlay on arrB
    float*  s_arr   = (float*)(smem + SARR_OFF_BYTES);    // [2049]
    float*  wtot    = (float*)(smem + WTOT_OFF_BYTES);    // [4]

    const int tid  = threadIdx.x;
    const int lane = tid & 63;
    const int w    = tid >> 6;
    const int q    = lane >> 5;
    const int col  = lane & 31;
    const float* xp = x + (size_t)blockIdx.x * FRAME;

    // ---- targeted zeroing of never-staged chunks (disjoint from staging: no extra barrier) ----
    if (tid < 64) {
        int sel = tid & 7;
        int c = (sel < 3) ? sel : sel + 257;              // {0,1,2,260..264}
        u32x4 z = {0u,0u,0u,0u};
        *(u32x4*)(arrA + (tid >> 3) * A_STRIDE + 8 * c) = z;
    } else if (tid < 191) {
        int B = tid + 193;                                // logical chunks 257..383
        u32x4 z = {0u,0u,0u,0u};
        *(u32x4*)(arrBb + 16 * (B + (B >> 3))) = z;
    }

    // ---- window load: xt[8tid-8 .. 8tid+7] ----
    f32x4 f0 = {0,0,0,0}, f1 = {0,0,0,0}, f2, f3;
    const f32x4* xv4 = (const f32x4*)(xp + 8 * tid - 8);
    if (tid != 0) { f0 = xv4[0]; f1 = xv4[1]; }
    f2 = xv4[2]; f3 = xv4[3];

    float xf[16];
    #pragma unroll
    for (int i = 0; i < 4; ++i) {
        xf[i] = f0[i]; xf[4+i] = f1[i]; xf[8+i] = f2[i]; xf[12+i] = f3[i];
    }
    // pack to bf16 dwords: W[j] = xb[2j] | xb[2j+1]<<16
    u32 W[8];
    #pragma unroll
    for (int j = 0; j < 8; ++j) {
        union { bf16_t h[2]; u32 u; } cv;
        cv.h[0] = (bf16_t)xf[2*j];
        cv.h[1] = (bf16_t)xf[2*j+1];
        W[j] = cv.u;
    }

    // ---- staging: 8 phase copies (A) + padded B copy, all b128 writes ----
    u32x4 D7;
    #pragma unroll
    for (int p = 0; p < 8; ++p) {
        int a = p >> 1;
        u32x4 D;
        if ((p & 1) == 0) {
            D[0] = W[a]; D[1] = W[a+1]; D[2] = W[a+2]; D[3] = W[a+3];
        } else {
            #pragma unroll
            for (int i = 0; i < 4; ++i)
                D[i] = (W[a+i] >> 16) | (W[a+i+1] << 16);
        }
        *(u32x4*)(arrA + p * A_STRIDE + 8 * (tid + 3)) = D;
        if (p == 7) D7 = D;
    }
    *(u32x4*)(arrBb + 16 * (tid + (tid >> 3))) = D7;      // logical chunk tid = window[7..14]

    if (tid == 255) {
        // A chunk 259 (tail): elements xb[8+p+j], zero beyond window
        #pragma unroll
        for (int p = 0; p < 8; ++p) {
            int a = p >> 1;
            u32x4 D;
            #pragma unroll
            for (int i = 0; i < 4; ++i) {
                int lo = 4 + a + i;
                if ((p & 1) == 0) {
                    D[i] = (lo <= 7) ? W[lo] : 0u;
                } else {
                    u32 x0 = (lo <= 7) ? (W[lo] >> 16) : 0u;
                    u32 x1 = (lo + 1 <= 7) ? (W[lo+1] << 16) : 0u;
                    D[i] = x0 | x1;
                }
            }
            *(u32x4*)(arrA + p * A_STRIDE + 8 * 259) = D;
        }
        u32x4 Db = { W[7] >> 16, 0u, 0u, 0u };            // B chunk 256 = [x2047, 0..]
        *(u32x4*)(arrBb + 16 * (256 + (256 >> 3))) = Db;
    }

    // ---- energy scan part 1 (own elements = xf[8..15]) ----
    float sq[8], pe[8];
    {
        float run = 0.f;
        #pragma unroll
        for (int e = 0; e < 8; ++e) {
            float v = xf[8 + e];
            sq[e] = v * v; run += sq[e]; pe[e] = run;
        }
    }
    float tsum = pe[7];
    float sc = tsum;
    #pragma unroll
    for (int off = 1; off < 64; off <<= 1) {
        float o = __shfl_up(sc, off, 64);
        if (lane >= off) sc += o;
    }
    if (lane == 63) wtot[w] = sc;
    float thr_off = sc - tsum;

    __syncthreads();   // staging + wtot complete

    // ---- energy scan part 2: exclusive prefix -> s_arr ----
    {
        float b0 = wtot[0], b1 = wtot[1], b2 = wtot[2];
        float base = (w > 0 ? b0 : 0.f) + (w > 1 ? b1 : 0.f) + (w > 2 ? b2 : 0.f) + thr_off;
        f32x4 sA, sB;
        #pragma unroll
        for (int i = 0; i < 4; ++i) {
            sA[i] = base + pe[i]   - sq[i];
            sB[i] = base + pe[4+i] - sq[4+i];
        }
        *(f32x4*)(s_arr + 8 * tid)     = sA;
        *(f32x4*)(s_arr + 8 * tid + 4) = sB;
        if (tid == 255) s_arr[2048] = base + pe[7];
    }

    // ---- MFMA K-loop: linear addressing, zero per-iter address math ----
    const bf16_t* aPtr = arrA + (col & 7) * A_STRIDE + (col & ~7) + 8 * q + 16 * w;
    int B0 = 2 * w + q + 4 * col;
    const bf16_t* bPtr = (const bf16_t*)arrBb + 8 * (B0 + (B0 >> 3));
    f32x16 acc0, acc1;
    #pragma unroll
    for (int v = 0; v < 16; ++v) { acc0[v] = 0.f; acc1[v] = 0.f; }

    int k = w;
    for (; k < 65; k += 4) {                 // both tiles
        bf16x8 av = *(const bf16x8*)aPtr;
        bf16x8 b0 = *(const bf16x8*)bPtr;
        bf16x8 b1 = *(const bf16x8*)(bPtr + 1152);
        acc0 = __builtin_amdgcn_mfma_f32_32x32x16_bf16(av, b0, acc0, 0, 0, 0);
        acc1 = __builtin_amdgcn_mfma_f32_32x32x16_bf16(av, b1, acc1, 0, 0, 0);
        aPtr += 64; bPtr += 72;
    }
    for (; k < 130; k += 4) {                // tile0 only
        bf16x8 av = *(const bf16x8*)aPtr;
        bf16x8 b0 = *(const bf16x8*)bPtr;
        acc0 = __builtin_amdgcn_mfma_f32_32x32x16_bf16(av, b0, acc0, 0, 0, 0);
        aPtr += 64; bPtr += 72;
    }

    __syncthreads();   // all waves done reading arrA/arrB

    // ---- partial writes: float4 groups (reg j=3..0 -> descending lags) ----
    float* prow = partial + w * P_STRIDE;
    #pragma unroll
    for (int g = 0; g < 4; ++g) {
        int L0 = 28 + 32 * col - 8 * g - 4 * q;
        int i0 = L0 + 4 * (L0 >> 5);
        f32x4 v0 = { acc0[4*g+3], acc0[4*g+2], acc0[4*g+1], acc0[4*g] };
        *(f32x4*)(prow + i0) = v0;
        int L1 = L0 + 1024;
        int i1 = L1 + 4 * (L1 >> 5);
        f32x4 v1 = { acc1[4*g+3], acc1[4*g+2], acc1[4*g+1], acc1[4*g] };
        *(f32x4*)(prow + i1) = v1;
    }
    __syncthreads();

    // ---- reduce partials, d_raw, scan part 1 ----
    const int tb = 8 * tid;
    const int ip = tb + 4 * (tb >> 5);
    f32x4 rA = {0,0,0,0}, rB = {0,0,0,0};
    #pragma unroll
    for (int ww = 0; ww < 4; ++ww) {
        rA += *(f32x4*)(partial + ww * P_STRIDE + ip);
        rB += *(f32x4*)(partial + ww * P_STRIDE + ip + 4);
    }
    const float sW = s_arr[2048];
    f32x4 s0v = *(f32x4*)(s_arr + tb);
    f32x4 s1v = *(f32x4*)(s_arr + tb + 4);
    f32x4 q0  = *(f32x4*)(s_arr + 2040 - tb);
    f32x4 q1  = *(f32x4*)(s_arr + 2044 - tb);
    float e0  = s_arr[2048 - tb];

    float dr[8], pe2[8];
    {
        float term1[8] = { e0, q1[3], q1[2], q1[1], q1[0], q0[3], q0[2], q0[1] };
        float rr[8] = { rA[0],rA[1],rA[2],rA[3], rB[0],rB[1],rB[2],rB[3] };
        float ss[8] = { s0v[0],s0v[1],s0v[2],s0v[3], s1v[0],s1v[1],s1v[2],s1v[3] };
        #pragma unroll
        for (int e = 0; e < 8; ++e)
            dr[e] = term1[e] + sW - ss[e] - 2.f * rr[e];
        if (tid == 0) dr[0] = 0.f;
        float run = 0.f;
        #pragma unroll
        for (int e = 0; e < 8; ++e) { run += dr[e]; pe2[e] = run; }
    }
    float tsum2 = pe2[7];
    float sc2 = tsum2;
    #pragma unroll
    for (int off = 1; off < 64; off <<= 1) {
        float o = __shfl_up(sc2, off, 64);
        if (lane >= off) sc2 += o;
    }
    if (lane == 63) wtot[w] = sc2;
    float thr2 = sc2 - tsum2;
    __syncthreads();

    // ---- scan part 2: normalize -> dbuf ----
    {
        float b0 = wtot[0], b1 = wtot[1], b2 = wtot[2];
        float base = (w > 0 ? b0 : 0.f) + (w > 1 ? b1 : 0.f) + (w > 2 ? b2 : 0.f) + thr2;
        f32x4 dA, dB;
        #pragma unroll
        for (int i = 0; i < 4; ++i) {
            float cumA = base + pe2[i];
            float cumB = base + pe2[4+i];
            dA[i] = (float)(tb + i)     * dr[i]   / (cumA + 1e-7f);
            dB[i] = (float)(tb + 4 + i) * dr[4+i] / (cumB + 1e-7f);
        }
        *(f32x4*)(dbuf + tb)     = dA;
        *(f32x4*)(dbuf + tb + 4) = dB;
    }
    __syncthreads();

    // ---- gather-interpolate ----
    float* op = out + (size_t)blockIdx.x * NOUT;
    if (use_tbl) {
        for (int m = tid; m < NOUT; m += 256) {
            int4 e = tbl[m];
            float wd = __int_as_float(e.z);
            float df = dbuf[e.x], dc = dbuf[e.y];
            op[m] = wd * (dc - df) + df;
        }
    } else {
        for (int m = tid; m < NOUT; m += 256) {
            double midi = 5.0 + (double)m * 0.05;
            float  mf   = (float)midi;
            double lag64 = 22050.0 / (440.0 * exp2(((double)mf - 69.0) / 12.0));
            float  lag  = (float)lag64;
            float  cf = ceilf(lag), ff = floorf(lag);
            float  dc = dbuf[(int)cf], df = dbuf[(int)ff];
            op[m] = (lag - ff) * (dc - df) / (cf - ff) + df;
        }
    }
}

__global__ void table_kernel(int4* __restrict__ tbl) {
    int m = blockIdx.x * 256 + threadIdx.x;
    if (m >= NOUT) return;
    double midi = 5.0 + (double)m * 0.05;            // mirrors np.arange fp64
    float  mf   = (float)midi;                       // .astype(float32)
    double lag64 = 22050.0 / (440.0 * exp2(((double)mf - 69.0) / 12.0));
    float  lag  = (float)lag64;                      // .astype(float32)
    float  cf = ceilf(lag), ff = floorf(lag);
    float  wd = (cf > ff) ? (lag - ff) / (cf - ff) : 0.f;
    int4 e; e.x = (int)ff; e.y = (int)cf; e.z = __float_as_int(wd); e.w = 0;
    tbl[m] = e;
}

extern "C" void kernel_launch(void* const* d_in, const int* in_sizes, int n_in,
                              void* d_out, int out_size, void* d_ws, size_t ws_size,
                              hipStream_t stream) {
    const float* x = (const float*)d_in[0];
    float* out = (float*)d_out;
    int frames = in_sizes[0] / FRAME;   // 16384
    int use_tbl = (ws_size >= (size_t)NOUT * sizeof(int4)) ? 1 : 0;
    int4* tbl = (int4*)d_ws;
    if (use_tbl)
        table_kernel<<<dim3((NOUT + 255) / 256), dim3(256), 0, stream>>>(tbl);
    yingram_kernel<<<dim3(frames), dim3(256), 0, stream>>>(x, out, tbl, use_tbl);
}